// Round 1
// baseline (1001.467 us; speedup 1.0000x reference)
//
#include <hip/hip_runtime.h>

#define T_SEQ 2048
#define DMODEL 2048
#define NH 16
#define NKV 4
#define HD 128
#define ISZ 5632
#define BATCH 2

typedef unsigned short ushort_t;
typedef __attribute__((ext_vector_type(8))) short short8;
typedef __attribute__((ext_vector_type(4))) float f32x4;

__device__ __forceinline__ ushort_t f2bf(float f) {
  unsigned int u = __float_as_uint(f);
  unsigned int r = (u + 0x7FFFu + ((u >> 16) & 1u)) >> 16;
  return (ushort_t)r;
}
__device__ __forceinline__ float bf2f(ushort_t h) {
  return __uint_as_float(((unsigned int)h) << 16);
}

// ---------------- weight fp32 (K,N) -> bf16 transposed (N,K) ----------------
__global__ __launch_bounds__(256) void wconv_kernel(const float* __restrict__ W,
                                                    ushort_t* __restrict__ Wt,
                                                    int K, int N) {
  __shared__ float tile[32][33];
  const int n0 = blockIdx.x * 32, k0 = blockIdx.y * 32;
  const int t = threadIdx.x;
  const int r = t >> 3, c = (t & 7) * 4;
  float4 v = *(const float4*)(W + (size_t)(k0 + r) * N + n0 + c);
  tile[r][c + 0] = v.x; tile[r][c + 1] = v.y; tile[r][c + 2] = v.z; tile[r][c + 3] = v.w;
  __syncthreads();
  ushort4 o;
  o.x = f2bf(tile[c + 0][r]);
  o.y = f2bf(tile[c + 1][r]);
  o.z = f2bf(tile[c + 2][r]);
  o.w = f2bf(tile[c + 3][r]);
  *(ushort4*)(Wt + (size_t)(n0 + r) * K + k0 + c) = o;
}

// ---------------- RMSNorm (f32 in, bf16 out), D = 2048, block = 256 ----------------
__global__ __launch_bounds__(256) void rmsnorm_kernel(const float* __restrict__ x,
                                                      const float* __restrict__ w,
                                                      ushort_t* __restrict__ out) {
  const int row = blockIdx.x;
  const int t = threadIdx.x;
  const float* xr = x + (size_t)row * DMODEL;
  float4 v0 = *(const float4*)(xr + t * 4);
  float4 v1 = *(const float4*)(xr + 1024 + t * 4);
  float ss = v0.x * v0.x + v0.y * v0.y + v0.z * v0.z + v0.w * v0.w +
             v1.x * v1.x + v1.y * v1.y + v1.z * v1.z + v1.w * v1.w;
  #pragma unroll
  for (int m = 1; m < 64; m <<= 1) ss += __shfl_xor(ss, m);
  __shared__ float red[4];
  if ((t & 63) == 0) red[t >> 6] = ss;
  __syncthreads();
  float tot = red[0] + red[1] + red[2] + red[3];
  float rinv = rsqrtf(tot * (1.0f / DMODEL) + 1e-5f);
  float4 w0 = *(const float4*)(w + t * 4);
  float4 w1 = *(const float4*)(w + 1024 + t * 4);
  ushort4 o0, o1;
  o0.x = f2bf(v0.x * rinv * w0.x); o0.y = f2bf(v0.y * rinv * w0.y);
  o0.z = f2bf(v0.z * rinv * w0.z); o0.w = f2bf(v0.w * rinv * w0.w);
  o1.x = f2bf(v1.x * rinv * w1.x); o1.y = f2bf(v1.y * rinv * w1.y);
  o1.z = f2bf(v1.z * rinv * w1.z); o1.w = f2bf(v1.w * rinv * w1.w);
  *(ushort4*)(out + (size_t)row * DMODEL + t * 4) = o0;
  *(ushort4*)(out + (size_t)row * DMODEL + 1024 + t * 4) = o1;
}

// ---------------- RoPE in place on bf16 buffer (B*T, nH, 128) ----------------
__global__ __launch_bounds__(256) void rope_kernel(ushort_t* __restrict__ buf,
                                                   const float* __restrict__ cs,
                                                   const float* __restrict__ sn,
                                                   int nH) {
  size_t idx = (size_t)blockIdx.x * 256 + threadIdx.x;
  int d = (int)(idx & 63);
  size_t rest = idx >> 6;
  int hh = (int)(rest % nH);
  size_t bt = rest / nH;
  int t = (int)(bt & (T_SEQ - 1));
  ushort_t* p = buf + (bt * nH + hh) * HD + 2 * d;
  float x1 = bf2f(p[0]), x2 = bf2f(p[1]);
  float c = cs[t * 64 + d], s = sn[t * 64 + d];
  p[0] = f2bf(x1 * c - x2 * s);
  p[1] = f2bf(x1 * s + x2 * c);
}

// ---------------- GEMM: A (M,K) bf16 row-major, Bt (N,K) bf16 row-major ----------------
// MODE 0: out bf16 = A@B + bias
// MODE 1: out f32  = res + A@B + bias
// MODE 2: out bf16 = silu(A@Bg + bias_g) * (A@Bu + bias_u)   (Bu rows at Bt + N*K, bias_u at bias+N)
#define BM 128
#define BN 128
#define BK 32

template <int MODE>
__global__ __launch_bounds__(256, 2)
void gemm_kernel(const ushort_t* __restrict__ A, const ushort_t* __restrict__ Bt,
                 const float* __restrict__ bias, const float* __restrict__ res,
                 void* __restrict__ outp, int M, int N, int K) {
  __shared__ ushort_t Alds[BM * BK];
  __shared__ ushort_t Blds[(MODE == 2 ? 2 : 1) * BM * BK];
  const int tid = threadIdx.x;
  const int w = tid >> 6, lane = tid & 63;
  const int lq = lane & 15, g = lane >> 4;
  const int m0 = blockIdx.y * BM, n0 = blockIdx.x * BN;
  const int ro = (w >> 1) * 64, co = (w & 1) * 64;

  f32x4 acc[4][4] = {};
  f32x4 acu[4][4] = {};

  for (int k0 = 0; k0 < K; k0 += BK) {
    const ushort_t* ga = A + (size_t)m0 * K + k0;
    const ushort_t* gb = Bt + (size_t)n0 * K + k0;
    const ushort_t* gu = Bt + ((size_t)N + n0) * K + k0;
    #pragma unroll
    for (int it = 0; it < 2; ++it) {
      int ch = it * 256 + tid;
      int row = ch >> 2, cir = ch & 3;
      size_t goff = (size_t)row * K + cir * 8;
      int lbase = (it * 256 + w * 64) * 8;  // elems; lane adds 16B each
      __builtin_amdgcn_global_load_lds(
          (const __attribute__((address_space(1))) void*)(ga + goff),
          (__attribute__((address_space(3))) void*)(&Alds[lbase]), 16, 0, 0);
      __builtin_amdgcn_global_load_lds(
          (const __attribute__((address_space(1))) void*)(gb + goff),
          (__attribute__((address_space(3))) void*)(&Blds[lbase]), 16, 0, 0);
      if (MODE == 2) {
        __builtin_amdgcn_global_load_lds(
            (const __attribute__((address_space(1))) void*)(gu + goff),
            (__attribute__((address_space(3))) void*)(&Blds[BM * BK + lbase]), 16, 0, 0);
      }
    }
    __syncthreads();
    short8 af[4], br[4];
    #pragma unroll
    for (int mi = 0; mi < 4; ++mi)
      af[mi] = *(const short8*)(&Alds[(ro + mi * 16 + lq) * BK + g * 8]);
    #pragma unroll
    for (int ni = 0; ni < 4; ++ni)
      br[ni] = *(const short8*)(&Blds[(co + ni * 16 + lq) * BK + g * 8]);
    #pragma unroll
    for (int mi = 0; mi < 4; ++mi)
      #pragma unroll
      for (int ni = 0; ni < 4; ++ni)
        acc[mi][ni] = __builtin_amdgcn_mfma_f32_16x16x32_bf16(af[mi], br[ni], acc[mi][ni], 0, 0, 0);
    if (MODE == 2) {
      short8 bu[4];
      #pragma unroll
      for (int ni = 0; ni < 4; ++ni)
        bu[ni] = *(const short8*)(&Blds[BM * BK + (co + ni * 16 + lq) * BK + g * 8]);
      #pragma unroll
      for (int mi = 0; mi < 4; ++mi)
        #pragma unroll
        for (int ni = 0; ni < 4; ++ni)
          acu[mi][ni] = __builtin_amdgcn_mfma_f32_16x16x32_bf16(af[mi], bu[ni], acu[mi][ni], 0, 0, 0);
    }
    __syncthreads();
  }

  #pragma unroll
  for (int ni = 0; ni < 4; ++ni) {
    int c = n0 + co + ni * 16 + lq;
    float bb = bias[c];
    float bu2 = (MODE == 2) ? bias[N + c] : 0.f;
    #pragma unroll
    for (int mi = 0; mi < 4; ++mi) {
      #pragma unroll
      for (int i = 0; i < 4; ++i) {
        int r = m0 + ro + mi * 16 + g * 4 + i;
        size_t oidx = (size_t)r * N + c;
        float av = acc[mi][ni][i] + bb;
        if (MODE == 0) {
          ((ushort_t*)outp)[oidx] = f2bf(av);
        } else if (MODE == 1) {
          ((float*)outp)[oidx] = res[oidx] + av;
        } else {
          float uu = acu[mi][ni][i] + bu2;
          float sl = av / (1.f + __expf(-av));
          ((ushort_t*)outp)[oidx] = f2bf(sl * uu);
        }
      }
    }
  }
}

// ---------------- Flash attention, GQA causal, MFMA 16x16x32 ----------------
// block: 256 thr = 4 waves, each wave 16 q rows; KV tiles of 32.
// Swapped S^T = mfma(K_frag, Q^T_frag): S^T C-layout -> lane holds q=lane&15.
#define QB 64
#define KB 32
#define KSTR 136  // 128 + 8 pad (keeps 16B align, 2-way bank alias = free)
#define VSTR 40   // 32 + 8 pad
#define PSTR 40

__global__ __launch_bounds__(256, 2)
void attn_kernel(const ushort_t* __restrict__ q, const ushort_t* __restrict__ kkv,
                 const ushort_t* __restrict__ vkv, ushort_t* __restrict__ ao) {
  __shared__ ushort_t Klds[KB * KSTR];
  __shared__ ushort_t Vt[HD * VSTR];
  __shared__ ushort_t Plds[4][16 * PSTR];

  const int tid = threadIdx.x;
  const int w = tid >> 6, lane = tid & 63;
  const int lq = lane & 15, g = lane >> 4;
  const int qb = blockIdx.x * QB;
  const int h = blockIdx.y;
  const int b = blockIdx.z;
  const int hkv = h >> 2;
  const int qw = qb + w * 16;
  const float scale = 0.08838834764831845f;

  short8 qf[4];
  {
    const ushort_t* qrow = q + ((size_t)(b * T_SEQ + qw + lq) * (NH * HD)) + h * HD;
    #pragma unroll
    for (int ks = 0; ks < 4; ++ks) qf[ks] = *(const short8*)(qrow + ks * 32 + g * 8);
  }

  f32x4 of[8] = {};
  float m_run = -1e30f, l_run = 0.f;

  const int nt = (qb + QB) >> 5;
  for (int ti = 0; ti < nt; ++ti) {
    const int kt = ti * KB;
    #pragma unroll
    for (int it = 0; it < 2; ++it) {
      int ch = it * 256 + tid;               // 512 chunks = 32 rows x 16
      int row = ch >> 4, dk = (ch & 15) * 8;
      size_t gidx = (size_t)(b * T_SEQ + kt + row) * (NKV * HD) + hkv * HD + dk;
      short8 k8 = *(const short8*)(kkv + gidx);
      *(short8*)(&Klds[row * KSTR + dk]) = k8;
      short8 v8 = *(const short8*)(vkv + gidx);
      #pragma unroll
      for (int j = 0; j < 8; ++j) Vt[(dk + j) * VSTR + row] = (ushort_t)v8[j];
    }
    __syncthreads();
    if (kt <= qw + 15) {
      f32x4 s[2] = {};
      #pragma unroll
      for (int c = 0; c < 2; ++c)
        #pragma unroll
        for (int ks = 0; ks < 4; ++ks) {
          short8 kf = *(const short8*)(&Klds[(c * 16 + lq) * KSTR + ks * 32 + g * 8]);
          s[c] = __builtin_amdgcn_mfma_f32_16x16x32_bf16(kf, qf[ks], s[c], 0, 0, 0);
        }
      const int qg = qw + lq;
      float sv[8];
      #pragma unroll
      for (int c = 0; c < 2; ++c)
        #pragma unroll
        for (int i = 0; i < 4; ++i) {
          int kvg = kt + c * 16 + 4 * g + i;
          float xx = s[c][i] * scale;
          sv[c * 4 + i] = (kvg > qg) ? -1e30f : xx;
        }
      float tmax = sv[0];
      #pragma unroll
      for (int j = 1; j < 8; ++j) tmax = fmaxf(tmax, sv[j]);
      tmax = fmaxf(tmax, __shfl_xor(tmax, 16));
      tmax = fmaxf(tmax, __shfl_xor(tmax, 32));
      float mnew = fmaxf(m_run, tmax);
      float corr = __expf(m_run - mnew);
      float pv[8];
      float ps = 0.f;
      #pragma unroll
      for (int j = 0; j < 8; ++j) { pv[j] = __expf(sv[j] - mnew); ps += pv[j]; }
      ps += __shfl_xor(ps, 16);
      ps += __shfl_xor(ps, 32);
      l_run = l_run * corr + ps;
      m_run = mnew;
      float c4[4];
      #pragma unroll
      for (int i = 0; i < 4; ++i) c4[i] = __shfl(corr, 4 * g + i);
      #pragma unroll
      for (int n = 0; n < 8; ++n)
        #pragma unroll
        for (int i = 0; i < 4; ++i) of[n][i] *= c4[i];
      #pragma unroll
      for (int c = 0; c < 2; ++c) {
        ushort4 pw;
        pw.x = f2bf(pv[c * 4 + 0]); pw.y = f2bf(pv[c * 4 + 1]);
        pw.z = f2bf(pv[c * 4 + 2]); pw.w = f2bf(pv[c * 4 + 3]);
        *(ushort4*)(&Plds[w][lq * PSTR + c * 16 + 4 * g]) = pw;
      }
      short8 pf = *(const short8*)(&Plds[w][lq * PSTR + g * 8]);
      #pragma unroll
      for (int n = 0; n < 8; ++n) {
        short8 vf = *(const short8*)(&Vt[(n * 16 + lq) * VSTR + g * 8]);
        of[n] = __builtin_amdgcn_mfma_f32_16x16x32_bf16(pf, vf, of[n], 0, 0, 0);
      }
    }
    __syncthreads();
  }
  float li[4];
  #pragma unroll
  for (int i = 0; i < 4; ++i) li[i] = 1.f / __shfl(l_run, 4 * g + i);
  #pragma unroll
  for (int n = 0; n < 8; ++n)
    #pragma unroll
    for (int i = 0; i < 4; ++i) {
      int tok = qw + 4 * g + i;
      ao[((size_t)(b * T_SEQ + tok) * (NH * HD)) + h * HD + n * 16 + lq] = f2bf(of[n][i] * li[i]);
    }
}

// ---------------- host ----------------
extern "C" void kernel_launch(void* const* d_in, const int* in_sizes, int n_in,
                              void* d_out, int out_size, void* d_ws, size_t ws_size,
                              hipStream_t stream) {
  const float* x   = (const float*)d_in[0];
  const float* rc  = (const float*)d_in[1];
  const float* rs  = (const float*)d_in[2];
  const float* ln1 = (const float*)d_in[3];
  const float* ln2 = (const float*)d_in[4];
  const float* wq  = (const float*)d_in[5];
  const float* wqb = (const float*)d_in[6];
  const float* wk  = (const float*)d_in[7];
  const float* wkb = (const float*)d_in[8];
  const float* wv  = (const float*)d_in[9];
  const float* wvb = (const float*)d_in[10];
  const float* wo  = (const float*)d_in[11];
  const float* wob = (const float*)d_in[12];
  const float* w1  = (const float*)d_in[13];
  const float* w1b = (const float*)d_in[14];
  const float* w2  = (const float*)d_in[15];
  const float* w2b = (const float*)d_in[16];

  char* ws = (char*)d_ws;
  size_t off = 0;
  auto alloc = [&](size_t bytes) {
    char* p = ws + off;
    off += (bytes + 255) & ~(size_t)255;
    return (void*)p;
  };
  const int M = BATCH * T_SEQ;  // 4096
  ushort_t* wqT = (ushort_t*)alloc((size_t)2048 * 2048 * 2);
  ushort_t* wkT = (ushort_t*)alloc((size_t)512 * 2048 * 2);
  ushort_t* wvT = (ushort_t*)alloc((size_t)512 * 2048 * 2);
  ushort_t* woT = (ushort_t*)alloc((size_t)2048 * 2048 * 2);
  ushort_t* w1T = (ushort_t*)alloc((size_t)11264 * 2048 * 2);
  ushort_t* w2T = (ushort_t*)alloc((size_t)2048 * 5632 * 2);
  ushort_t* hbuf = (ushort_t*)alloc((size_t)M * 2048 * 2);  // h, later ao
  ushort_t* qbuf = (ushort_t*)alloc((size_t)M * 2048 * 2);  // q, later g
  ushort_t* kbuf = (ushort_t*)alloc((size_t)M * 512 * 2);
  ushort_t* vbuf = (ushort_t*)alloc((size_t)M * 512 * 2);
  float*    h1   = (float*)alloc((size_t)M * 2048 * 4);
  ushort_t* act  = (ushort_t*)alloc((size_t)M * 5632 * 2);
  if (off > ws_size) return;  // workspace too small; fail loudly (output stays poisoned)

  // weight transpose-converts
  wconv_kernel<<<dim3(2048 / 32, 2048 / 32), 256, 0, stream>>>(wq, wqT, 2048, 2048);
  wconv_kernel<<<dim3(512 / 32, 2048 / 32), 256, 0, stream>>>(wk, wkT, 2048, 512);
  wconv_kernel<<<dim3(512 / 32, 2048 / 32), 256, 0, stream>>>(wv, wvT, 2048, 512);
  wconv_kernel<<<dim3(2048 / 32, 2048 / 32), 256, 0, stream>>>(wo, woT, 2048, 2048);
  wconv_kernel<<<dim3(11264 / 32, 2048 / 32), 256, 0, stream>>>(w1, w1T, 2048, 11264);
  wconv_kernel<<<dim3(2048 / 32, 5632 / 32), 256, 0, stream>>>(w2, w2T, 5632, 2048);

  rmsnorm_kernel<<<M, 256, 0, stream>>>(x, ln1, hbuf);

  gemm_kernel<0><<<dim3(2048 / BN, M / BM), 256, 0, stream>>>(hbuf, wqT, wqb, nullptr, qbuf, M, 2048, 2048);
  gemm_kernel<0><<<dim3(512 / BN, M / BM), 256, 0, stream>>>(hbuf, wkT, wkb, nullptr, kbuf, M, 512, 2048);
  gemm_kernel<0><<<dim3(512 / BN, M / BM), 256, 0, stream>>>(hbuf, wvT, wvb, nullptr, vbuf, M, 512, 2048);

  rope_kernel<<<(M * NH * 64) / 256, 256, 0, stream>>>(qbuf, rc, rs, NH);
  rope_kernel<<<(M * NKV * 64) / 256, 256, 0, stream>>>(kbuf, rc, rs, NKV);

  attn_kernel<<<dim3(T_SEQ / QB, NH, BATCH), 256, 0, stream>>>(qbuf, kbuf, vbuf, hbuf);

  gemm_kernel<1><<<dim3(2048 / BN, M / BM), 256, 0, stream>>>(hbuf, woT, wob, x, h1, M, 2048, 2048);

  rmsnorm_kernel<<<M, 256, 0, stream>>>(h1, ln2, qbuf);  // g

  gemm_kernel<2><<<dim3(5632 / BN, M / BM), 256, 0, stream>>>(qbuf, w1T, w1b, nullptr, act, M, 5632, 2048);

  gemm_kernel<1><<<dim3(2048 / BN, M / BM), 256, 0, stream>>>(act, w2T, w2b, h1, (float*)d_out, M, 2048, 5632);

  (void)in_sizes; (void)n_in; (void)out_size;
}

// Round 2
// 783.300 us; speedup vs baseline: 1.2785x; 1.2785x over previous
//
#include <hip/hip_runtime.h>

#define T_SEQ 2048
#define DMODEL 2048
#define NH 16
#define NKV 4
#define HD 128
#define ISZ 5632
#define BATCH 2

typedef unsigned short ushort_t;
typedef __attribute__((ext_vector_type(8))) short short8;
typedef __attribute__((ext_vector_type(4))) float f32x4;

__device__ __forceinline__ ushort_t f2bf(float f) {
  unsigned int u = __float_as_uint(f);
  unsigned int r = (u + 0x7FFFu + ((u >> 16) & 1u)) >> 16;
  return (ushort_t)r;
}
__device__ __forceinline__ float bf2f(ushort_t h) {
  return __uint_as_float(((unsigned int)h) << 16);
}

// ---------------- weight fp32 (K,N) -> bf16 transposed (N,K) ----------------
__global__ __launch_bounds__(256) void wconv_kernel(const float* __restrict__ W,
                                                    ushort_t* __restrict__ Wt,
                                                    int K, int N) {
  __shared__ float tile[32][33];
  const int n0 = blockIdx.x * 32, k0 = blockIdx.y * 32;
  const int t = threadIdx.x;
  const int r = t >> 3, c = (t & 7) * 4;
  float4 v = *(const float4*)(W + (size_t)(k0 + r) * N + n0 + c);
  tile[r][c + 0] = v.x; tile[r][c + 1] = v.y; tile[r][c + 2] = v.z; tile[r][c + 3] = v.w;
  __syncthreads();
  ushort4 o;
  o.x = f2bf(tile[c + 0][r]);
  o.y = f2bf(tile[c + 1][r]);
  o.z = f2bf(tile[c + 2][r]);
  o.w = f2bf(tile[c + 3][r]);
  *(ushort4*)(Wt + (size_t)(n0 + r) * K + k0 + c) = o;
}

// ---------------- RMSNorm (f32 in, bf16 out), D = 2048, block = 256 ----------------
__global__ __launch_bounds__(256) void rmsnorm_kernel(const float* __restrict__ x,
                                                      const float* __restrict__ w,
                                                      ushort_t* __restrict__ out) {
  const int row = blockIdx.x;
  const int t = threadIdx.x;
  const float* xr = x + (size_t)row * DMODEL;
  float4 v0 = *(const float4*)(xr + t * 4);
  float4 v1 = *(const float4*)(xr + 1024 + t * 4);
  float ss = v0.x * v0.x + v0.y * v0.y + v0.z * v0.z + v0.w * v0.w +
             v1.x * v1.x + v1.y * v1.y + v1.z * v1.z + v1.w * v1.w;
  #pragma unroll
  for (int m = 1; m < 64; m <<= 1) ss += __shfl_xor(ss, m);
  __shared__ float red[4];
  if ((t & 63) == 0) red[t >> 6] = ss;
  __syncthreads();
  float tot = red[0] + red[1] + red[2] + red[3];
  float rinv = rsqrtf(tot * (1.0f / DMODEL) + 1e-5f);
  float4 w0 = *(const float4*)(w + t * 4);
  float4 w1 = *(const float4*)(w + 1024 + t * 4);
  ushort4 o0, o1;
  o0.x = f2bf(v0.x * rinv * w0.x); o0.y = f2bf(v0.y * rinv * w0.y);
  o0.z = f2bf(v0.z * rinv * w0.z); o0.w = f2bf(v0.w * rinv * w0.w);
  o1.x = f2bf(v1.x * rinv * w1.x); o1.y = f2bf(v1.y * rinv * w1.y);
  o1.z = f2bf(v1.z * rinv * w1.z); o1.w = f2bf(v1.w * rinv * w1.w);
  *(ushort4*)(out + (size_t)row * DMODEL + t * 4) = o0;
  *(ushort4*)(out + (size_t)row * DMODEL + 1024 + t * 4) = o1;
}

// ---------------- RoPE in place on bf16 buffer (B*T, nH, 128) ----------------
__global__ __launch_bounds__(256) void rope_kernel(ushort_t* __restrict__ buf,
                                                   const float* __restrict__ cs,
                                                   const float* __restrict__ sn,
                                                   int nH) {
  size_t idx = (size_t)blockIdx.x * 256 + threadIdx.x;
  int d = (int)(idx & 63);
  size_t rest = idx >> 6;
  int hh = (int)(rest % nH);
  size_t bt = rest / nH;
  int t = (int)(bt & (T_SEQ - 1));
  ushort_t* p = buf + (bt * nH + hh) * HD + 2 * d;
  float x1 = bf2f(p[0]), x2 = bf2f(p[1]);
  float c = cs[t * 64 + d], s = sn[t * 64 + d];
  p[0] = f2bf(x1 * c - x2 * s);
  p[1] = f2bf(x1 * s + x2 * c);
}

// ---------------- GEMM: A (M,K) bf16 row-major, Bt (N,K) bf16 row-major ----------------
// MODE 0: out bf16 = A@B + bias
// MODE 1: out f32  = res + A@B + bias
// MODE 2: out bf16 = silu(A@Bg + bias_g) * (A@Bu + bias_u)   (Bu rows at Bt + N*K, bias_u at bias+N)
// MODE 3: out bf16 = A@B + bias, written TRANSPOSED per-kv-head: out[((b*NKV+hkv)*HD+d)*T_SEQ + t]
#define BM 128
#define BN 128
#define BK 32

template <int MODE>
__global__ __launch_bounds__(256, 2)
void gemm_kernel(const ushort_t* __restrict__ A, const ushort_t* __restrict__ Bt,
                 const float* __restrict__ bias, const float* __restrict__ res,
                 void* __restrict__ outp, int M, int N, int K) {
  __shared__ ushort_t Alds[BM * BK];
  __shared__ ushort_t Blds[(MODE == 2 ? 2 : 1) * BM * BK];
  const int tid = threadIdx.x;
  const int w = tid >> 6, lane = tid & 63;
  const int lq = lane & 15, g = lane >> 4;
  const int m0 = blockIdx.y * BM, n0 = blockIdx.x * BN;
  const int ro = (w >> 1) * 64, co = (w & 1) * 64;

  f32x4 acc[4][4] = {};
  f32x4 acu[4][4] = {};

  for (int k0 = 0; k0 < K; k0 += BK) {
    const ushort_t* ga = A + (size_t)m0 * K + k0;
    const ushort_t* gb = Bt + (size_t)n0 * K + k0;
    const ushort_t* gu = Bt + ((size_t)N + n0) * K + k0;
    #pragma unroll
    for (int it = 0; it < 2; ++it) {
      int ch = it * 256 + tid;
      int row = ch >> 2, cir = ch & 3;
      size_t goff = (size_t)row * K + cir * 8;
      int lbase = (it * 256 + w * 64) * 8;  // elems; lane adds 16B each
      __builtin_amdgcn_global_load_lds(
          (const __attribute__((address_space(1))) void*)(ga + goff),
          (__attribute__((address_space(3))) void*)(&Alds[lbase]), 16, 0, 0);
      __builtin_amdgcn_global_load_lds(
          (const __attribute__((address_space(1))) void*)(gb + goff),
          (__attribute__((address_space(3))) void*)(&Blds[lbase]), 16, 0, 0);
      if (MODE == 2) {
        __builtin_amdgcn_global_load_lds(
            (const __attribute__((address_space(1))) void*)(gu + goff),
            (__attribute__((address_space(3))) void*)(&Blds[BM * BK + lbase]), 16, 0, 0);
      }
    }
    __syncthreads();
    short8 af[4], br[4];
    #pragma unroll
    for (int mi = 0; mi < 4; ++mi)
      af[mi] = *(const short8*)(&Alds[(ro + mi * 16 + lq) * BK + g * 8]);
    #pragma unroll
    for (int ni = 0; ni < 4; ++ni)
      br[ni] = *(const short8*)(&Blds[(co + ni * 16 + lq) * BK + g * 8]);
    #pragma unroll
    for (int mi = 0; mi < 4; ++mi)
      #pragma unroll
      for (int ni = 0; ni < 4; ++ni)
        acc[mi][ni] = __builtin_amdgcn_mfma_f32_16x16x32_bf16(af[mi], br[ni], acc[mi][ni], 0, 0, 0);
    if (MODE == 2) {
      short8 bu[4];
      #pragma unroll
      for (int ni = 0; ni < 4; ++ni)
        bu[ni] = *(const short8*)(&Blds[BM * BK + (co + ni * 16 + lq) * BK + g * 8]);
      #pragma unroll
      for (int mi = 0; mi < 4; ++mi)
        #pragma unroll
        for (int ni = 0; ni < 4; ++ni)
          acu[mi][ni] = __builtin_amdgcn_mfma_f32_16x16x32_bf16(af[mi], bu[ni], acu[mi][ni], 0, 0, 0);
    }
    __syncthreads();
  }

  #pragma unroll
  for (int ni = 0; ni < 4; ++ni) {
    int c = n0 + co + ni * 16 + lq;
    float bb = bias[c];
    float bu2 = (MODE == 2) ? bias[N + c] : 0.f;
    #pragma unroll
    for (int mi = 0; mi < 4; ++mi) {
      #pragma unroll
      for (int i = 0; i < 4; ++i) {
        int r = m0 + ro + mi * 16 + g * 4 + i;
        size_t oidx = (size_t)r * N + c;
        float av = acc[mi][ni][i] + bb;
        if (MODE == 0) {
          ((ushort_t*)outp)[oidx] = f2bf(av);
        } else if (MODE == 1) {
          ((float*)outp)[oidx] = res[oidx] + av;
        } else if (MODE == 3) {
          int b2 = r >> 11, t2 = r & (T_SEQ - 1);
          int hk = c >> 7, dd = c & (HD - 1);
          ((ushort_t*)outp)[((size_t)(b2 * NKV + hk) * HD + dd) * T_SEQ + t2] = f2bf(av);
        } else {
          float uu = acu[mi][ni][i] + bu2;
          float sl = av / (1.f + __expf(-av));
          ((ushort_t*)outp)[oidx] = f2bf(sl * uu);
        }
      }
    }
  }
}

// ---------------- Flash attention, GQA causal, MFMA 16x16x32 ----------------
// 256 thr = 4 waves, each wave 16 q rows; KV tiles of 64; V pre-transposed in global.
#define QB 64
#define KB 64
#define KSTR 136  // 128 + 8 pad -> b128 reads at bank floor
#define VSTR 72   // 64 + 8 pad
#define PSTR 72

__global__ __launch_bounds__(256, 2)
void attn_kernel(const ushort_t* __restrict__ q, const ushort_t* __restrict__ kkv,
                 const ushort_t* __restrict__ vT, ushort_t* __restrict__ ao) {
  __shared__ ushort_t Klds[KB * KSTR];
  __shared__ ushort_t Vlds[HD * VSTR];
  __shared__ ushort_t Plds[4][16 * PSTR];

  const int tid = threadIdx.x;
  const int w = tid >> 6, lane = tid & 63;
  const int lq = lane & 15, g = lane >> 4;
  const int nqb = T_SEQ / QB;
  const int xq = blockIdx.x;
  const int qi = (xq & 1) ? (nqb - 1 - (xq >> 1)) : (xq >> 1);  // pair light/heavy tiles
  const int qb = qi * QB;
  const int h = blockIdx.y;
  const int b = blockIdx.z;
  const int hkv = h >> 2;
  const int qw = qb + w * 16;
  const float scale = 0.08838834764831845f;

  short8 qf[4];
  {
    const ushort_t* qrow = q + ((size_t)(b * T_SEQ + qw + lq) * (NH * HD)) + h * HD;
    #pragma unroll
    for (int ks = 0; ks < 4; ++ks) qf[ks] = *(const short8*)(qrow + ks * 32 + g * 8);
  }

  f32x4 of[8] = {};
  float m_run = -1e30f, l_run = 0.f;

  const ushort_t* kbase = kkv + (size_t)b * T_SEQ * (NKV * HD) + hkv * HD;
  const ushort_t* vbase = vT + (size_t)(b * NKV + hkv) * HD * T_SEQ;

  const int nt = (qb + QB) / KB;
  for (int ti = 0; ti < nt; ++ti) {
    const int kt = ti * KB;
    #pragma unroll
    for (int it = 0; it < 4; ++it) {
      int ch = it * 256 + tid;  // 1024 chunks of 8 elems
      int krow = ch >> 4, kdk = (ch & 15) * 8;
      *(short8*)(&Klds[krow * KSTR + kdk]) =
          *(const short8*)(kbase + (size_t)(kt + krow) * (NKV * HD) + kdk);
      int vd = ch >> 3, vj = (ch & 7) * 8;
      *(short8*)(&Vlds[vd * VSTR + vj]) =
          *(const short8*)(vbase + (size_t)vd * T_SEQ + kt + vj);
    }
    __syncthreads();
    if (kt <= qw + 15) {
      f32x4 s[4] = {};
      __builtin_amdgcn_s_setprio(1);
      #pragma unroll
      for (int c = 0; c < 4; ++c)
        #pragma unroll
        for (int ks = 0; ks < 4; ++ks) {
          short8 kf = *(const short8*)(&Klds[(c * 16 + lq) * KSTR + ks * 32 + g * 8]);
          s[c] = __builtin_amdgcn_mfma_f32_16x16x32_bf16(kf, qf[ks], s[c], 0, 0, 0);
        }
      __builtin_amdgcn_s_setprio(0);
      const int qg = qw + lq;
      float sv[16];
      #pragma unroll
      for (int c = 0; c < 4; ++c)
        #pragma unroll
        for (int i = 0; i < 4; ++i) {
          int kvg = kt + c * 16 + 4 * g + i;
          float xx = s[c][i] * scale;
          sv[c * 4 + i] = (kvg > qg) ? -1e30f : xx;
        }
      float tmax = sv[0];
      #pragma unroll
      for (int j = 1; j < 16; ++j) tmax = fmaxf(tmax, sv[j]);
      tmax = fmaxf(tmax, __shfl_xor(tmax, 16));
      tmax = fmaxf(tmax, __shfl_xor(tmax, 32));
      float mnew = fmaxf(m_run, tmax);
      float corr = __expf(m_run - mnew);
      float pv[16];
      float ps = 0.f;
      #pragma unroll
      for (int j = 0; j < 16; ++j) { pv[j] = __expf(sv[j] - mnew); ps += pv[j]; }
      ps += __shfl_xor(ps, 16);
      ps += __shfl_xor(ps, 32);
      l_run = l_run * corr + ps;
      m_run = mnew;
      float c4[4];
      #pragma unroll
      for (int i = 0; i < 4; ++i) c4[i] = __shfl(corr, 4 * g + i);
      #pragma unroll
      for (int n = 0; n < 8; ++n)
        #pragma unroll
        for (int i = 0; i < 4; ++i) of[n][i] *= c4[i];
      #pragma unroll
      for (int c = 0; c < 4; ++c) {
        ushort4 pw;
        pw.x = f2bf(pv[c * 4 + 0]); pw.y = f2bf(pv[c * 4 + 1]);
        pw.z = f2bf(pv[c * 4 + 2]); pw.w = f2bf(pv[c * 4 + 3]);
        *(ushort4*)(&Plds[w][lq * PSTR + c * 16 + 4 * g]) = pw;
      }
      short8 pf0 = *(const short8*)(&Plds[w][lq * PSTR + g * 8]);
      short8 pf1 = *(const short8*)(&Plds[w][lq * PSTR + 32 + g * 8]);
      __builtin_amdgcn_s_setprio(1);
      #pragma unroll
      for (int n = 0; n < 8; ++n) {
        short8 vf0 = *(const short8*)(&Vlds[(n * 16 + lq) * VSTR + g * 8]);
        short8 vf1 = *(const short8*)(&Vlds[(n * 16 + lq) * VSTR + 32 + g * 8]);
        of[n] = __builtin_amdgcn_mfma_f32_16x16x32_bf16(pf0, vf0, of[n], 0, 0, 0);
        of[n] = __builtin_amdgcn_mfma_f32_16x16x32_bf16(pf1, vf1, of[n], 0, 0, 0);
      }
      __builtin_amdgcn_s_setprio(0);
    }
    __syncthreads();
  }
  float li[4];
  #pragma unroll
  for (int i = 0; i < 4; ++i) li[i] = 1.f / __shfl(l_run, 4 * g + i);
  #pragma unroll
  for (int n = 0; n < 8; ++n)
    #pragma unroll
    for (int i = 0; i < 4; ++i) {
      int tok = qw + 4 * g + i;
      ao[((size_t)(b * T_SEQ + tok) * (NH * HD)) + h * HD + n * 16 + lq] = f2bf(of[n][i] * li[i]);
    }
}

// ---------------- host ----------------
extern "C" void kernel_launch(void* const* d_in, const int* in_sizes, int n_in,
                              void* d_out, int out_size, void* d_ws, size_t ws_size,
                              hipStream_t stream) {
  const float* x   = (const float*)d_in[0];
  const float* rc  = (const float*)d_in[1];
  const float* rs  = (const float*)d_in[2];
  const float* ln1 = (const float*)d_in[3];
  const float* ln2 = (const float*)d_in[4];
  const float* wq  = (const float*)d_in[5];
  const float* wqb = (const float*)d_in[6];
  const float* wk  = (const float*)d_in[7];
  const float* wkb = (const float*)d_in[8];
  const float* wv  = (const float*)d_in[9];
  const float* wvb = (const float*)d_in[10];
  const float* wo  = (const float*)d_in[11];
  const float* wob = (const float*)d_in[12];
  const float* w1  = (const float*)d_in[13];
  const float* w1b = (const float*)d_in[14];
  const float* w2  = (const float*)d_in[15];
  const float* w2b = (const float*)d_in[16];

  char* ws = (char*)d_ws;
  size_t off = 0;
  auto alloc = [&](size_t bytes) {
    char* p = ws + off;
    off += (bytes + 255) & ~(size_t)255;
    return (void*)p;
  };
  const int M = BATCH * T_SEQ;  // 4096
  ushort_t* wqT = (ushort_t*)alloc((size_t)2048 * 2048 * 2);
  ushort_t* wkT = (ushort_t*)alloc((size_t)512 * 2048 * 2);
  ushort_t* wvT = (ushort_t*)alloc((size_t)512 * 2048 * 2);
  ushort_t* woT = (ushort_t*)alloc((size_t)2048 * 2048 * 2);
  ushort_t* w1T = (ushort_t*)alloc((size_t)11264 * 2048 * 2);
  ushort_t* w2T = (ushort_t*)alloc((size_t)2048 * 5632 * 2);
  ushort_t* hbuf = (ushort_t*)alloc((size_t)M * 2048 * 2);  // h, later ao
  ushort_t* qbuf = (ushort_t*)alloc((size_t)M * 2048 * 2);  // q, later g
  ushort_t* kbuf = (ushort_t*)alloc((size_t)M * 512 * 2);
  ushort_t* vbufT = (ushort_t*)alloc((size_t)M * 512 * 2);  // V^T: (b,hkv,d,t)
  float*    h1   = (float*)alloc((size_t)M * 2048 * 4);
  ushort_t* act  = (ushort_t*)alloc((size_t)M * 5632 * 2);
  if (off > ws_size) return;  // workspace too small; fail loudly (output stays poisoned)

  // weight transpose-converts
  wconv_kernel<<<dim3(2048 / 32, 2048 / 32), 256, 0, stream>>>(wq, wqT, 2048, 2048);
  wconv_kernel<<<dim3(512 / 32, 2048 / 32), 256, 0, stream>>>(wk, wkT, 2048, 512);
  wconv_kernel<<<dim3(512 / 32, 2048 / 32), 256, 0, stream>>>(wv, wvT, 2048, 512);
  wconv_kernel<<<dim3(2048 / 32, 2048 / 32), 256, 0, stream>>>(wo, woT, 2048, 2048);
  wconv_kernel<<<dim3(11264 / 32, 2048 / 32), 256, 0, stream>>>(w1, w1T, 2048, 11264);
  wconv_kernel<<<dim3(2048 / 32, 5632 / 32), 256, 0, stream>>>(w2, w2T, 5632, 2048);

  rmsnorm_kernel<<<M, 256, 0, stream>>>(x, ln1, hbuf);

  gemm_kernel<0><<<dim3(2048 / BN, M / BM), 256, 0, stream>>>(hbuf, wqT, wqb, nullptr, qbuf, M, 2048, 2048);
  gemm_kernel<0><<<dim3(512 / BN, M / BM), 256, 0, stream>>>(hbuf, wkT, wkb, nullptr, kbuf, M, 512, 2048);
  gemm_kernel<3><<<dim3(512 / BN, M / BM), 256, 0, stream>>>(hbuf, wvT, wvb, nullptr, vbufT, M, 512, 2048);

  rope_kernel<<<(M * NH * 64) / 256, 256, 0, stream>>>(qbuf, rc, rs, NH);
  rope_kernel<<<(M * NKV * 64) / 256, 256, 0, stream>>>(kbuf, rc, rs, NKV);

  attn_kernel<<<dim3(T_SEQ / QB, NH, BATCH), 256, 0, stream>>>(qbuf, kbuf, vbufT, hbuf);

  gemm_kernel<1><<<dim3(2048 / BN, M / BM), 256, 0, stream>>>(hbuf, woT, wob, x, h1, M, 2048, 2048);

  rmsnorm_kernel<<<M, 256, 0, stream>>>(h1, ln2, qbuf);  // g

  gemm_kernel<2><<<dim3(5632 / BN, M / BM), 256, 0, stream>>>(qbuf, w1T, w1b, nullptr, act, M, 5632, 2048);

  gemm_kernel<1><<<dim3(2048 / BN, M / BM), 256, 0, stream>>>(act, w2T, w2b, h1, (float*)d_out, M, 2048, 5632);

  (void)in_sizes; (void)n_in; (void)out_size;
}

// Round 3
// 749.028 us; speedup vs baseline: 1.3370x; 1.0458x over previous
//
#include <hip/hip_runtime.h>

#define T_SEQ 2048
#define DMODEL 2048
#define NH 16
#define NKV 4
#define HD 128
#define ISZ 5632
#define BATCH 2
#define QKS 2560  // fused q|k row stride

typedef unsigned short ushort_t;
typedef __attribute__((ext_vector_type(8))) short short8;
typedef __attribute__((ext_vector_type(4))) float f32x4;

__device__ __forceinline__ ushort_t f2bf(float f) {
  unsigned int u = __float_as_uint(f);
  unsigned int r = (u + 0x7FFFu + ((u >> 16) & 1u)) >> 16;
  return (ushort_t)r;
}
__device__ __forceinline__ float bf2f(ushort_t h) {
  return __uint_as_float(((unsigned int)h) << 16);
}

// ---------------- weight fp32 (K,N) -> bf16 transposed (N,K) ----------------
__global__ __launch_bounds__(256) void wconv_kernel(const float* __restrict__ W,
                                                    ushort_t* __restrict__ Wt,
                                                    int K, int N) {
  __shared__ float tile[32][33];
  const int n0 = blockIdx.x * 32, k0 = blockIdx.y * 32;
  const int t = threadIdx.x;
  const int r = t >> 3, c = (t & 7) * 4;
  float4 v = *(const float4*)(W + (size_t)(k0 + r) * N + n0 + c);
  tile[r][c + 0] = v.x; tile[r][c + 1] = v.y; tile[r][c + 2] = v.z; tile[r][c + 3] = v.w;
  __syncthreads();
  ushort4 o;
  o.x = f2bf(tile[c + 0][r]);
  o.y = f2bf(tile[c + 1][r]);
  o.z = f2bf(tile[c + 2][r]);
  o.w = f2bf(tile[c + 3][r]);
  *(ushort4*)(Wt + (size_t)(n0 + r) * K + k0 + c) = o;
}

__global__ __launch_bounds__(256) void catbias_kernel(const float* __restrict__ a,
                                                      const float* __restrict__ b,
                                                      float* __restrict__ o) {
  int i = blockIdx.x * 256 + threadIdx.x;
  if (i < QKS) o[i] = (i < 2048) ? a[i] : b[i - 2048];
}

// ---------------- RMSNorm (f32 in, bf16 out), D = 2048, block = 256 ----------------
__global__ __launch_bounds__(256) void rmsnorm_kernel(const float* __restrict__ x,
                                                      const float* __restrict__ w,
                                                      ushort_t* __restrict__ out) {
  const int row = blockIdx.x;
  const int t = threadIdx.x;
  const float* xr = x + (size_t)row * DMODEL;
  float4 v0 = *(const float4*)(xr + t * 4);
  float4 v1 = *(const float4*)(xr + 1024 + t * 4);
  float ss = v0.x * v0.x + v0.y * v0.y + v0.z * v0.z + v0.w * v0.w +
             v1.x * v1.x + v1.y * v1.y + v1.z * v1.z + v1.w * v1.w;
  #pragma unroll
  for (int m = 1; m < 64; m <<= 1) ss += __shfl_xor(ss, m);
  __shared__ float red[4];
  if ((t & 63) == 0) red[t >> 6] = ss;
  __syncthreads();
  float tot = red[0] + red[1] + red[2] + red[3];
  float rinv = rsqrtf(tot * (1.0f / DMODEL) + 1e-5f);
  float4 w0 = *(const float4*)(w + t * 4);
  float4 w1 = *(const float4*)(w + 1024 + t * 4);
  ushort4 o0, o1;
  o0.x = f2bf(v0.x * rinv * w0.x); o0.y = f2bf(v0.y * rinv * w0.y);
  o0.z = f2bf(v0.z * rinv * w0.z); o0.w = f2bf(v0.w * rinv * w0.w);
  o1.x = f2bf(v1.x * rinv * w1.x); o1.y = f2bf(v1.y * rinv * w1.y);
  o1.z = f2bf(v1.z * rinv * w1.z); o1.w = f2bf(v1.w * rinv * w1.w);
  *(ushort4*)(out + (size_t)row * DMODEL + t * 4) = o0;
  *(ushort4*)(out + (size_t)row * DMODEL + 1024 + t * 4) = o1;
}

// ---------------- RoPE in place on fused q|k buffer (B*T, 20 head-slots, 128) ----------------
__global__ __launch_bounds__(256) void rope_kernel(ushort_t* __restrict__ buf,
                                                   const float* __restrict__ cs,
                                                   const float* __restrict__ sn) {
  size_t idx = (size_t)blockIdx.x * 256 + threadIdx.x;
  int d = (int)(idx & 63);
  size_t rest = idx >> 6;
  int hh = (int)(rest % 20);
  size_t bt = rest / 20;
  int t = (int)(bt & (T_SEQ - 1));
  ushort_t* p = buf + bt * QKS + hh * HD + 2 * d;
  float x1 = bf2f(p[0]), x2 = bf2f(p[1]);
  float c = cs[t * 64 + d], s = sn[t * 64 + d];
  p[0] = f2bf(x1 * c - x2 * s);
  p[1] = f2bf(x1 * s + x2 * c);
}

// ---------------- SwiGLU in place: gu[:, :I] = silu(gu[:, :I]) * gu[:, I:] ----------------
__global__ __launch_bounds__(256) void swiglu_kernel(ushort_t* __restrict__ gu) {
  size_t i = (size_t)blockIdx.x * 256 + threadIdx.x;  // one short8 of the gate half
  size_t m = i / (ISZ / 8);
  size_t j = (i % (ISZ / 8)) * 8;
  ushort_t* pg = gu + m * (2 * ISZ) + j;
  short8 gg = *(const short8*)pg;
  short8 uu = *(const short8*)(pg + ISZ);
  short8 oo;
  #pragma unroll
  for (int q = 0; q < 8; ++q) {
    float gv = bf2f((ushort_t)gg[q]);
    float uv = bf2f((ushort_t)uu[q]);
    float sl = gv / (1.f + __expf(-gv));
    oo[q] = (short)f2bf(sl * uv);
  }
  *(short8*)pg = oo;
}

// ================= 256x256 deep-pipelined GEMM (8 waves, BK=64, swizzled LDS) =============
// A (M,K) bf16 row-major w/ stride lda; Bt (N,K) bf16 row-major; out bf16 = A@B + bias.
__device__ __forceinline__ short8 ldsw(const char* base, int row, int colb) {
  int o = row * 128 + colb;
  o ^= ((o >> 7) & 7) << 4;  // st-swizzle (involution)
  return *(const short8*)(base + o);
}

__global__ __launch_bounds__(512, 2)
void gemm256_kernel(const ushort_t* __restrict__ A, int lda,
                    const ushort_t* __restrict__ Bt,
                    const float* __restrict__ bias, void* __restrict__ outp,
                    int M, int N, int K) {
  __shared__ ushort_t lds[65536];  // 128 KiB: [buf0: A 32K | B 32K][buf1: A | B]
  const int tid = threadIdx.x;
  const int wid = tid >> 6, lane = tid & 63;
  const int lq = lane & 15, g = lane >> 4;
  const int wm = wid >> 2, wn = wid & 3;
  const int m0 = blockIdx.y * 256, n0 = blockIdx.x * 256;
  const int NT = K >> 6;

  auto stage = [&](int t, int p) {
    const char* sa = (const char*)(A + (size_t)m0 * lda + t * 64);
    const char* sb = (const char*)(Bt + (size_t)n0 * K + t * 64);
    char* lb = (char*)lds + p * 65536;
    #pragma unroll
    for (int j = 0; j < 4; ++j) {
      int pb = (wid * 4 + j) * 1024 + lane * 16;   // linear dest byte in matrix region
      int ob = pb ^ (((pb >> 7) & 7) << 4);        // pre-swizzled logical source
      int row = ob >> 7, colb = ob & 127;
      __builtin_amdgcn_global_load_lds(
          (const __attribute__((address_space(1))) void*)(sa + (size_t)row * (lda * 2) + colb),
          (__attribute__((address_space(3))) void*)(lb + (wid * 4 + j) * 1024), 16, 0, 0);
      __builtin_amdgcn_global_load_lds(
          (const __attribute__((address_space(1))) void*)(sb + (size_t)row * (K * 2) + colb),
          (__attribute__((address_space(3))) void*)(lb + 32768 + (wid * 4 + j) * 1024), 16, 0, 0);
    }
  };

  f32x4 acc[8][4] = {};
  stage(0, 0);
  int p = 0;
  for (int t = 0; t < NT; ++t) {
    asm volatile("s_waitcnt vmcnt(0)" ::: "memory");   // tile t landed (issued 4 phases ago)
    __builtin_amdgcn_s_barrier();                      // all waves done reading buf p^1
    if (t + 1 < NT) stage(t + 1, p ^ 1);               // prefetch next tile (never waited early)
    const char* Ab = (const char*)lds + p * 65536;
    const char* Bb = Ab + 32768;
    short8 aA[4][2], bB[2][2][2];
    // phase 0: A(qm=0) + B(qn=0); MFMA quad (0,0)
    #pragma unroll
    for (int mi = 0; mi < 4; ++mi)
      #pragma unroll
      for (int ks = 0; ks < 2; ++ks)
        aA[mi][ks] = ldsw(Ab, wm * 128 + mi * 16 + lq, ks * 64 + g * 16);
    #pragma unroll
    for (int nj = 0; nj < 2; ++nj)
      #pragma unroll
      for (int ks = 0; ks < 2; ++ks)
        bB[0][nj][ks] = ldsw(Bb, wn * 64 + nj * 16 + lq, ks * 64 + g * 16);
    __builtin_amdgcn_s_setprio(1);
    #pragma unroll
    for (int mi = 0; mi < 4; ++mi)
      #pragma unroll
      for (int nj = 0; nj < 2; ++nj)
        #pragma unroll
        for (int ks = 0; ks < 2; ++ks)
          acc[mi][nj] = __builtin_amdgcn_mfma_f32_16x16x32_bf16(aA[mi][ks], bB[0][nj][ks], acc[mi][nj], 0, 0, 0);
    __builtin_amdgcn_s_setprio(0);
    __builtin_amdgcn_s_barrier();
    // phase 1: B(qn=1); MFMA quad (0,1)
    #pragma unroll
    for (int nj = 0; nj < 2; ++nj)
      #pragma unroll
      for (int ks = 0; ks < 2; ++ks)
        bB[1][nj][ks] = ldsw(Bb, wn * 64 + 32 + nj * 16 + lq, ks * 64 + g * 16);
    __builtin_amdgcn_s_setprio(1);
    #pragma unroll
    for (int mi = 0; mi < 4; ++mi)
      #pragma unroll
      for (int nj = 0; nj < 2; ++nj)
        #pragma unroll
        for (int ks = 0; ks < 2; ++ks)
          acc[mi][2 + nj] = __builtin_amdgcn_mfma_f32_16x16x32_bf16(aA[mi][ks], bB[1][nj][ks], acc[mi][2 + nj], 0, 0, 0);
    __builtin_amdgcn_s_setprio(0);
    __builtin_amdgcn_s_barrier();
    // phase 2: A(qm=1); MFMA quad (1,0)
    #pragma unroll
    for (int mi = 0; mi < 4; ++mi)
      #pragma unroll
      for (int ks = 0; ks < 2; ++ks)
        aA[mi][ks] = ldsw(Ab, wm * 128 + 64 + mi * 16 + lq, ks * 64 + g * 16);
    __builtin_amdgcn_s_setprio(1);
    #pragma unroll
    for (int mi = 0; mi < 4; ++mi)
      #pragma unroll
      for (int nj = 0; nj < 2; ++nj)
        #pragma unroll
        for (int ks = 0; ks < 2; ++ks)
          acc[4 + mi][nj] = __builtin_amdgcn_mfma_f32_16x16x32_bf16(aA[mi][ks], bB[0][nj][ks], acc[4 + mi][nj], 0, 0, 0);
    __builtin_amdgcn_s_setprio(0);
    __builtin_amdgcn_s_barrier();
    // phase 3: MFMA quad (1,1)
    __builtin_amdgcn_s_setprio(1);
    #pragma unroll
    for (int mi = 0; mi < 4; ++mi)
      #pragma unroll
      for (int nj = 0; nj < 2; ++nj)
        #pragma unroll
        for (int ks = 0; ks < 2; ++ks)
          acc[4 + mi][2 + nj] = __builtin_amdgcn_mfma_f32_16x16x32_bf16(aA[mi][ks], bB[1][nj][ks], acc[4 + mi][2 + nj], 0, 0, 0);
    __builtin_amdgcn_s_setprio(0);
    p ^= 1;
  }

  #pragma unroll
  for (int nf = 0; nf < 4; ++nf) {
    int c = n0 + wn * 64 + nf * 16 + lq;
    float bb = bias[c];
    #pragma unroll
    for (int mf = 0; mf < 8; ++mf) {
      #pragma unroll
      for (int i = 0; i < 4; ++i) {
        int r = m0 + wm * 128 + mf * 16 + g * 4 + i;
        ((ushort_t*)outp)[(size_t)r * N + c] = f2bf(acc[mf][nf][i] + bb);
      }
    }
  }
}

// ---------------- 128x128 GEMM (kept for Wo / W2 / V: full-grid shapes) ----------------
// MODE 1: out f32 = res + A@B + bias;  MODE 3: bf16 out written V^T per-kv-head
#define BM 128
#define BN 128
#define BK 32

template <int MODE>
__global__ __launch_bounds__(256, 2)
void gemm_kernel(const ushort_t* __restrict__ A, int lda, const ushort_t* __restrict__ Bt,
                 const float* __restrict__ bias, const float* __restrict__ res,
                 void* __restrict__ outp, int M, int N, int K) {
  __shared__ ushort_t Alds[BM * BK];
  __shared__ ushort_t Blds[BM * BK];
  const int tid = threadIdx.x;
  const int w = tid >> 6, lane = tid & 63;
  const int lq = lane & 15, g = lane >> 4;
  const int m0 = blockIdx.y * BM, n0 = blockIdx.x * BN;
  const int ro = (w >> 1) * 64, co = (w & 1) * 64;

  f32x4 acc[4][4] = {};

  for (int k0 = 0; k0 < K; k0 += BK) {
    const ushort_t* ga = A + (size_t)m0 * lda + k0;
    const ushort_t* gb = Bt + (size_t)n0 * K + k0;
    #pragma unroll
    for (int it = 0; it < 2; ++it) {
      int ch = it * 256 + tid;
      int row = ch >> 2, cir = ch & 3;
      int lbase = (it * 256 + w * 64) * 8;
      __builtin_amdgcn_global_load_lds(
          (const __attribute__((address_space(1))) void*)(ga + (size_t)row * lda + cir * 8),
          (__attribute__((address_space(3))) void*)(&Alds[lbase]), 16, 0, 0);
      __builtin_amdgcn_global_load_lds(
          (const __attribute__((address_space(1))) void*)(gb + (size_t)row * K + cir * 8),
          (__attribute__((address_space(3))) void*)(&Blds[lbase]), 16, 0, 0);
    }
    __syncthreads();
    short8 af[4], br[4];
    #pragma unroll
    for (int mi = 0; mi < 4; ++mi)
      af[mi] = *(const short8*)(&Alds[(ro + mi * 16 + lq) * BK + g * 8]);
    #pragma unroll
    for (int ni = 0; ni < 4; ++ni)
      br[ni] = *(const short8*)(&Blds[(co + ni * 16 + lq) * BK + g * 8]);
    #pragma unroll
    for (int mi = 0; mi < 4; ++mi)
      #pragma unroll
      for (int ni = 0; ni < 4; ++ni)
        acc[mi][ni] = __builtin_amdgcn_mfma_f32_16x16x32_bf16(af[mi], br[ni], acc[mi][ni], 0, 0, 0);
    __syncthreads();
  }

  #pragma unroll
  for (int ni = 0; ni < 4; ++ni) {
    int c = n0 + co + ni * 16 + lq;
    float bb = bias[c];
    #pragma unroll
    for (int mi = 0; mi < 4; ++mi) {
      #pragma unroll
      for (int i = 0; i < 4; ++i) {
        int r = m0 + ro + mi * 16 + g * 4 + i;
        size_t oidx = (size_t)r * N + c;
        float av = acc[mi][ni][i] + bb;
        if (MODE == 1) {
          ((float*)outp)[oidx] = res[oidx] + av;
        } else {  // MODE 3
          int b2 = r >> 11, t2 = r & (T_SEQ - 1);
          int hk = c >> 7, dd = c & (HD - 1);
          ((ushort_t*)outp)[((size_t)(b2 * NKV + hk) * HD + dd) * T_SEQ + t2] = f2bf(av);
        }
      }
    }
  }
}

// ---------------- Flash attention, GQA causal, MFMA 16x16x32 ----------------
#define QB 64
#define KB 64
#define KSTR 136
#define VSTR 72
#define PSTR 72

__global__ __launch_bounds__(256, 2)
void attn_kernel(const ushort_t* __restrict__ qk, const ushort_t* __restrict__ vT,
                 ushort_t* __restrict__ ao) {
  __shared__ ushort_t Klds[KB * KSTR];
  __shared__ ushort_t Vlds[HD * VSTR];
  __shared__ ushort_t Plds[4][16 * PSTR];

  const int tid = threadIdx.x;
  const int w = tid >> 6, lane = tid & 63;
  const int lq = lane & 15, g = lane >> 4;
  const int nqb = T_SEQ / QB;
  const int xq = blockIdx.x;
  const int qi = (xq & 1) ? (nqb - 1 - (xq >> 1)) : (xq >> 1);
  const int qb = qi * QB;
  const int h = blockIdx.y;
  const int b = blockIdx.z;
  const int hkv = h >> 2;
  const int qw = qb + w * 16;
  const float scale = 0.08838834764831845f;

  short8 qf[4];
  {
    const ushort_t* qrow = qk + ((size_t)(b * T_SEQ + qw + lq) * QKS) + h * HD;
    #pragma unroll
    for (int ks = 0; ks < 4; ++ks) qf[ks] = *(const short8*)(qrow + ks * 32 + g * 8);
  }

  f32x4 of[8] = {};
  float m_run = -1e30f, l_run = 0.f;

  const ushort_t* kbase = qk + (size_t)b * T_SEQ * QKS + 2048 + hkv * HD;
  const ushort_t* vbase = vT + (size_t)(b * NKV + hkv) * HD * T_SEQ;

  const int nt = (qb + QB) / KB;
  for (int ti = 0; ti < nt; ++ti) {
    const int kt = ti * KB;
    #pragma unroll
    for (int it = 0; it < 4; ++it) {
      int ch = it * 256 + tid;
      int krow = ch >> 4, kdk = (ch & 15) * 8;
      *(short8*)(&Klds[krow * KSTR + kdk]) =
          *(const short8*)(kbase + (size_t)(kt + krow) * QKS + kdk);
      int vd = ch >> 3, vj = (ch & 7) * 8;
      *(short8*)(&Vlds[vd * VSTR + vj]) =
          *(const short8*)(vbase + (size_t)vd * T_SEQ + kt + vj);
    }
    __syncthreads();
    if (kt <= qw + 15) {
      f32x4 s[4] = {};
      __builtin_amdgcn_s_setprio(1);
      #pragma unroll
      for (int c = 0; c < 4; ++c)
        #pragma unroll
        for (int ks = 0; ks < 4; ++ks) {
          short8 kf = *(const short8*)(&Klds[(c * 16 + lq) * KSTR + ks * 32 + g * 8]);
          s[c] = __builtin_amdgcn_mfma_f32_16x16x32_bf16(kf, qf[ks], s[c], 0, 0, 0);
        }
      __builtin_amdgcn_s_setprio(0);
      const int qg = qw + lq;
      float sv[16];
      #pragma unroll
      for (int c = 0; c < 4; ++c)
        #pragma unroll
        for (int i = 0; i < 4; ++i) {
          int kvg = kt + c * 16 + 4 * g + i;
          float xx = s[c][i] * scale;
          sv[c * 4 + i] = (kvg > qg) ? -1e30f : xx;
        }
      float tmax = sv[0];
      #pragma unroll
      for (int j = 1; j < 16; ++j) tmax = fmaxf(tmax, sv[j]);
      tmax = fmaxf(tmax, __shfl_xor(tmax, 16));
      tmax = fmaxf(tmax, __shfl_xor(tmax, 32));
      float mnew = fmaxf(m_run, tmax);
      float corr = __expf(m_run - mnew);
      float pv[16];
      float ps = 0.f;
      #pragma unroll
      for (int j = 0; j < 16; ++j) { pv[j] = __expf(sv[j] - mnew); ps += pv[j]; }
      ps += __shfl_xor(ps, 16);
      ps += __shfl_xor(ps, 32);
      l_run = l_run * corr + ps;
      m_run = mnew;
      float c4[4];
      #pragma unroll
      for (int i = 0; i < 4; ++i) c4[i] = __shfl(corr, 4 * g + i);
      #pragma unroll
      for (int n = 0; n < 8; ++n)
        #pragma unroll
        for (int i = 0; i < 4; ++i) of[n][i] *= c4[i];
      #pragma unroll
      for (int c = 0; c < 4; ++c) {
        ushort4 pw;
        pw.x = f2bf(pv[c * 4 + 0]); pw.y = f2bf(pv[c * 4 + 1]);
        pw.z = f2bf(pv[c * 4 + 2]); pw.w = f2bf(pv[c * 4 + 3]);
        *(ushort4*)(&Plds[w][lq * PSTR + c * 16 + 4 * g]) = pw;
      }
      short8 pf0 = *(const short8*)(&Plds[w][lq * PSTR + g * 8]);
      short8 pf1 = *(const short8*)(&Plds[w][lq * PSTR + 32 + g * 8]);
      __builtin_amdgcn_s_setprio(1);
      #pragma unroll
      for (int n = 0; n < 8; ++n) {
        short8 vf0 = *(const short8*)(&Vlds[(n * 16 + lq) * VSTR + g * 8]);
        short8 vf1 = *(const short8*)(&Vlds[(n * 16 + lq) * VSTR + 32 + g * 8]);
        of[n] = __builtin_amdgcn_mfma_f32_16x16x32_bf16(pf0, vf0, of[n], 0, 0, 0);
        of[n] = __builtin_amdgcn_mfma_f32_16x16x32_bf16(pf1, vf1, of[n], 0, 0, 0);
      }
      __builtin_amdgcn_s_setprio(0);
    }
    __syncthreads();
  }
  float li[4];
  #pragma unroll
  for (int i = 0; i < 4; ++i) li[i] = 1.f / __shfl(l_run, 4 * g + i);
  #pragma unroll
  for (int n = 0; n < 8; ++n)
    #pragma unroll
    for (int i = 0; i < 4; ++i) {
      int tok = qw + 4 * g + i;
      ao[((size_t)(b * T_SEQ + tok) * (NH * HD)) + h * HD + n * 16 + lq] = f2bf(of[n][i] * li[i]);
    }
}

// ---------------- host ----------------
extern "C" void kernel_launch(void* const* d_in, const int* in_sizes, int n_in,
                              void* d_out, int out_size, void* d_ws, size_t ws_size,
                              hipStream_t stream) {
  const float* x   = (const float*)d_in[0];
  const float* rc  = (const float*)d_in[1];
  const float* rs  = (const float*)d_in[2];
  const float* ln1 = (const float*)d_in[3];
  const float* ln2 = (const float*)d_in[4];
  const float* wq  = (const float*)d_in[5];
  const float* wqb = (const float*)d_in[6];
  const float* wk  = (const float*)d_in[7];
  const float* wkb = (const float*)d_in[8];
  const float* wv  = (const float*)d_in[9];
  const float* wvb = (const float*)d_in[10];
  const float* wo  = (const float*)d_in[11];
  const float* wob = (const float*)d_in[12];
  const float* w1  = (const float*)d_in[13];
  const float* w1b = (const float*)d_in[14];
  const float* w2  = (const float*)d_in[15];
  const float* w2b = (const float*)d_in[16];

  char* ws = (char*)d_ws;
  size_t off = 0;
  auto alloc = [&](size_t bytes) {
    char* p = ws + off;
    off += (bytes + 255) & ~(size_t)255;
    return (void*)p;
  };
  const int M = BATCH * T_SEQ;  // 4096
  ushort_t* w1T  = (ushort_t*)alloc((size_t)11264 * 2048 * 2);
  ushort_t* w2T  = (ushort_t*)alloc((size_t)2048 * 5632 * 2);
  ushort_t* hbuf = (ushort_t*)alloc((size_t)M * 2048 * 2);    // h -> ao -> g
  ushort_t* vbufT= (ushort_t*)alloc((size_t)M * 512 * 2);     // V^T (b,hkv,d,t)
  float*    qkb  = (float*)alloc((size_t)QKS * 4);
  // --- overlay region: [wqkT | wvT | woT | qkbuf | extra] reused as gu after attention ---
  size_t guStart = off;
  ushort_t* wqkT = (ushort_t*)alloc((size_t)QKS * 2048 * 2);
  ushort_t* wvT  = (ushort_t*)alloc((size_t)512 * 2048 * 2);
  ushort_t* woT  = (ushort_t*)alloc((size_t)2048 * 2048 * 2);
  ushort_t* qkbuf= (ushort_t*)alloc((size_t)M * QKS * 2);
  size_t guBytes = (size_t)M * 11264 * 2;
  size_t used = off - guStart;
  if (guBytes > used) alloc(guBytes - used);
  ushort_t* gu = (ushort_t*)(ws + guStart);
  float* h1 = (float*)d_out;  // residual stream lives in d_out
  if (off > ws_size) return;

  // weight transpose-converts
  wconv_kernel<<<dim3(2048 / 32, 2048 / 32), 256, 0, stream>>>(wq, wqkT, 2048, 2048);
  wconv_kernel<<<dim3(512 / 32, 2048 / 32), 256, 0, stream>>>(wk, wqkT + (size_t)2048 * 2048, 2048, 512);
  wconv_kernel<<<dim3(512 / 32, 2048 / 32), 256, 0, stream>>>(wv, wvT, 2048, 512);
  wconv_kernel<<<dim3(2048 / 32, 2048 / 32), 256, 0, stream>>>(wo, woT, 2048, 2048);
  wconv_kernel<<<dim3(11264 / 32, 2048 / 32), 256, 0, stream>>>(w1, w1T, 2048, 11264);
  wconv_kernel<<<dim3(2048 / 32, 5632 / 32), 256, 0, stream>>>(w2, w2T, 5632, 2048);
  catbias_kernel<<<10, 256, 0, stream>>>(wqb, wkb, qkb);

  rmsnorm_kernel<<<M, 256, 0, stream>>>(x, ln1, hbuf);

  // fused Q|K projection (N=2560) on the 256^2 pipeline; V on 128^2 with transposed write
  gemm256_kernel<<<dim3(QKS / 256, M / 256), 512, 0, stream>>>(hbuf, 2048, wqkT, qkb, qkbuf, M, QKS, 2048);
  gemm_kernel<3><<<dim3(512 / BN, M / BM), 256, 0, stream>>>(hbuf, 2048, wvT, wvb, nullptr, vbufT, M, 512, 2048);

  rope_kernel<<<(M * 20 * 64) / 256, 256, 0, stream>>>(qkbuf, rc, rs);

  attn_kernel<<<dim3(T_SEQ / QB, NH, BATCH), 256, 0, stream>>>(qkbuf, vbufT, hbuf);

  gemm_kernel<1><<<dim3(2048 / BN, M / BM), 256, 0, stream>>>(hbuf, 2048, woT, wob, x, h1, M, 2048, 2048);

  rmsnorm_kernel<<<M, 256, 0, stream>>>(h1, ln2, hbuf);  // g

  gemm256_kernel<<<dim3(11264 / 256, M / 256), 512, 0, stream>>>(hbuf, 2048, w1T, w1b, gu, M, 11264, 2048);

  swiglu_kernel<<<(M * (ISZ / 8)) / 256, 256, 0, stream>>>(gu);

  gemm_kernel<1><<<dim3(2048 / BN, M / BM), 256, 0, stream>>>(gu, 11264, w2T, w2b, h1, (float*)d_out, M, 2048, 5632);

  (void)in_sizes; (void)n_in; (void)out_size;
}